// Round 1
// baseline (2103.092 us; speedup 1.0000x reference)
//
#include <hip/hip_runtime.h>
#include <math.h>

// Problem constants: N=20000, E=320000, C=64, NS=4, NB=8, NH=64
#define PI_F        3.14159265358979323846f
#define SQRT2_F     1.41421356237309515f
#define SQRT3_F     1.73205080756887729f
#define INV_SQRT3_F 0.57735026918962576f
#define INV_AVG     0.25f   // 1/sqrt(16)

#define N_NODES 20000
#define N_EDGES 320000

__device__ __forceinline__ float swish_f(float x) {
    // fast rcp: ~2^-22 rel err, negligible vs absmax budget
    return x * __builtin_amdgcn_rcpf(1.f + __expf(-x));
}

// ---------------------------------------------------------------------------
// Edge counting sort by receiver (round-2, known good).
// ---------------------------------------------------------------------------
__global__ __launch_bounds__(256) void k_zero_cnt(int* __restrict__ cnt) {
    const int i = blockIdx.x * 256 + threadIdx.x;
    if (i < N_NODES) cnt[i] = 0;
}
__global__ __launch_bounds__(256) void k_hist(const int* __restrict__ rcv,
                                              int* __restrict__ cnt) {
    const int e = blockIdx.x * 256 + threadIdx.x;
    if (e < N_EDGES) atomicAdd(&cnt[rcv[e]], 1);
}
__global__ __launch_bounds__(1024) void k_scan(const int* __restrict__ cnt,
                                               int* __restrict__ cursor) {
    __shared__ int part[1024];
    const int t = threadIdx.x;
    const int base = t * 20;
    int s = 0;
    #pragma unroll
    for (int j = 0; j < 20; ++j) {
        const int idx = base + j;
        if (idx < N_NODES) s += cnt[idx];
    }
    part[t] = s;
    __syncthreads();
    for (int d = 1; d < 1024; d <<= 1) {
        const int v = (t >= d) ? part[t - d] : 0;
        __syncthreads();
        part[t] += v;
        __syncthreads();
    }
    int run = (t == 0) ? 0 : part[t - 1];
    for (int j = 0; j < 20; ++j) {
        const int idx = base + j;
        if (idx < N_NODES) { cursor[idx] = run; run += cnt[idx]; }
    }
}
__global__ __launch_bounds__(256) void k_scatter(const int* __restrict__ rcv,
                                                 int* __restrict__ cursor,
                                                 int* __restrict__ perm) {
    const int e = blockIdx.x * 256 + threadIdx.x;
    if (e < N_EDGES) {
        const int pos = atomicAdd(&cursor[rcv[e]], 1);
        perm[pos] = e;
    }
}

// ---------------------------------------------------------------------------
// K1: node up-projection + agg zero-init (round-2, known good).
// ---------------------------------------------------------------------------
__global__ __launch_bounds__(256) void k_node_up(
    const float* __restrict__ ns, const float* __restrict__ nv,
    const float* __restrict__ Wus, const float* __restrict__ Wuv,
    float* __restrict__ s_up, float* __restrict__ v_up,
    float* __restrict__ agg_s, float* __restrict__ agg_v)
{
    const int lane = threadIdx.x & 63;
    const int wq   = __builtin_amdgcn_readfirstlane(threadIdx.x >> 6);
    const int n    = blockIdx.x * 4 + wq;

    const float* nsr = ns + n * 64;
    const float* nvr = nv + n * 192;
    float acc = 0.f, a0 = 0.f, a1 = 0.f, a2 = 0.f;
    for (int i = 0; i < 64; ++i) {
        const float s = nsr[i];
        acc = fmaf(s, Wus[i*64 + lane], acc);
        const float wv = Wuv[i*64 + lane];
        a0 = fmaf(nvr[i*3+0], wv, a0);
        a1 = fmaf(nvr[i*3+1], wv, a1);
        a2 = fmaf(nvr[i*3+2], wv, a2);
    }
    s_up[n*64 + lane] = acc;
    v_up[(n*64 + lane)*3 + 0] = a0;
    v_up[(n*64 + lane)*3 + 1] = a1;
    v_up[(n*64 + lane)*3 + 2] = a2;

    agg_s[n*128 + lane]      = 0.f;
    agg_s[n*128 + 64 + lane] = 0.f;
    #pragma unroll
    for (int k = 0; k < 6; ++k) agg_v[n*384 + k*64 + lane] = 0.f;
}

// ---------------------------------------------------------------------------
// K2 v7 (OCCUPANCY): v6 ALL-f32 VALU MLP, but with a single in-place LDS
// buffer hv[64*69] (h2 overwrites h1 row-by-row after A2's reads complete)
// and __launch_bounds__(256, 8).
//   v6 was capped at 4 blocks/CU by BOTH the 35,328 B dual buffer AND
//   launch_bounds(256,4) -> Occupancy 40%, VALUBusy 74% (26% issue-idle on
//   gather/shuffle/atomic latency). Halving LDS to 17,664 B + bounds(256,8)
//   allows 8 blocks/CU = 32 waves. VGPR was exactly 64 under (256,4), which
//   is the 8-waves/SIMD step, so the cap change should not force spills.
// In-place safety: A2 of wave wq reads ALL of rows wq*16..wq*16+15 (full i
// loop) before writing any h2 value into those same rows; DS ops from one
// wave complete in order, and the compiler cannot reorder same-array
// accesses it can't disjoint-prove. Cross-wave h2 reads (phase B) are
// covered by the existing __syncthreads().
//  A1: bessel+W0 -> hv rows of own wave.  A2: h1@W1 (reads only own rows ->
//  NO barrier after A1), overwrites own rows with h2.  B: mixr[t][ntl]
//  computed directly in the phase-C register layout: lane (c,q) of wave wq
//  holds mix[64wq+ntl*16+c][le=q*16+t].
//  C: per-q-group segmented register accumulation + atomic flush (v5).
// ---------------------------------------------------------------------------
__global__ __launch_bounds__(256, 8) void k_edge(
    const float* __restrict__ vecs,
    const int*   __restrict__ snd_idx, const int* __restrict__ rcv_idx,
    const int*   __restrict__ perm,
    const float* __restrict__ W0, const float* __restrict__ W1,
    const float* __restrict__ W2,
    const float* __restrict__ s_up, const float* __restrict__ v_up,
    float* __restrict__ agg_s, float* __restrict__ agg_v)
{
    __shared__ float hv[64*69];   // [le][i], stride 69; holds h1 then h2

    const int tid  = threadIdx.x;
    const int lane = tid & 63;
    const int wq   = __builtin_amdgcn_readfirstlane(tid >> 6);
    const int e0   = blockIdx.x * 64;
    const int c    = lane & 15, q = lane >> 4;

    // --- per-lane metadata for sorted slot e0+lane (all 64 edges) ---
    const int pe_l  = perm[e0 + lane];
    const int rcv_l = rcv_idx[pe_l];
    const int snd_l = snd_idx[pe_l];
    const float vx_l = vecs[pe_l*3+0], vy_l = vecs[pe_l*3+1], vz_l = vecs[pe_l*3+2];
    const float x_l  = sqrtf(vx_l*vx_l + vy_l*vy_l + vz_l*vz_l);
    const float sx_l = (x_l == 0.f) ? 1.f : x_l;
    const float ys_l = SQRT3_F / sx_l;
    const float Y0_l = vx_l * ys_l, Y1_l = vy_l * ys_l, Y2_l = vz_l * ys_l;
    const float msk_l = (x_l == 0.f) ? 0.f : 1.f;

    // ---- A1: bessel + layer0 -> hv[le][lane] (=h1), le = wq*16 + t ----
    #pragma unroll 4
    for (int t = 0; t < 16; ++t) {
        const int le = wq*16 + t;
        const float x = __shfl(x_l, le);
        const float sx = (x == 0.f) ? 1.f : x;
        float s1, c1;
        __sincosf(PI_F * x, &s1, &c1);
        const float u  = fminf(x, 1.f);
        const float u2 = u*u, u3 = u2*u;
        const float u6 = u3*u3, u7 = u6*u, u8 = u6*u2;
        const float env  = (x < 1.f) ? (1.f - 28.f*u6 + 48.f*u7 - 21.f*u8) : 0.f;
        const float pref = SQRT2_F * env / sx;
        float h1 = 0.f;
        float sn = s1, snm1 = 0.f;
        const float twoc = 2.f * c1;
        #pragma unroll
        for (int b = 0; b < 8; ++b) {
            h1 = fmaf(pref * sn, W0[b*64 + lane], h1);
            const float snext = fmaf(twoc, sn, -snm1);
            snm1 = sn; sn = snext;
        }
        hv[le*69 + lane] = swish_f(h1);
    }
    // no barrier: A2 reads only this wave's own rows (compiler waits lgkmcnt)

    // ---- A2: h2 = swish(h1 @ W1), own rows, lane = output channel ----
    // reads rows wq*16..wq*16+15 fully, THEN overwrites them with h2.
    {
        float acc2[16];
        #pragma unroll
        for (int t = 0; t < 16; ++t) acc2[t] = 0.f;
        for (int i = 0; i < 64; ++i) {
            const float w = W1[i*64 + lane];           // coalesced, L1-hot
            #pragma unroll
            for (int t = 0; t < 16; ++t)
                acc2[t] = fmaf(hv[(wq*16 + t)*69 + i], w, acc2[t]);
        }
        #pragma unroll
        for (int t = 0; t < 16; ++t)
            hv[(wq*16 + t)*69 + lane] = swish_f(acc2[t]);
    }
    __syncthreads();

    // ---- B: mixr[t][ntl] = mix[64wq + ntl*16 + c][le = q*16 + t] ----
    float mixr[16][4];
    #pragma unroll
    for (int t = 0; t < 16; ++t)
        #pragma unroll
        for (int j = 0; j < 4; ++j) mixr[t][j] = 0.f;
    {
        const float* W2c = W2 + 64*wq + c;
        for (int i = 0; i < 64; ++i) {
            const float w0 = W2c[i*256 +  0];
            const float w1 = W2c[i*256 + 16];
            const float w2 = W2c[i*256 + 32];
            const float w3 = W2c[i*256 + 48];
            #pragma unroll
            for (int t = 0; t < 16; ++t) {
                const float h = hv[(q*16 + t)*69 + i];
                mixr[t][0] = fmaf(h, w0, mixr[t][0]);
                mixr[t][1] = fmaf(h, w1, mixr[t][1]);
                mixr[t][2] = fmaf(h, w2, mixr[t][2]);
                mixr[t][3] = fmaf(h, w3, mixr[t][3]);
            }
        }
    }

    // ---- C: per-q-group segmented scatter-add from registers (v5) ----
    int cur = -1;
    if (wq == 0) {            // agg_s[:, ntl*16+c] += msv * mix0
        float ra0=0.f, ra1=0.f, ra2=0.f, ra3=0.f;
        #pragma unroll
        for (int t = 0; t < 16; ++t) {
            const int sl  = (lane & 48) + t;
            const int rcv = __shfl(rcv_l, sl);
            const int snd = __shfl(snd_l, sl);
            const float msk = __shfl(msk_l, sl);
            if (rcv != cur) {
                if (cur >= 0) {
                    float* p = agg_s + cur*128 + c;
                    unsafeAtomicAdd(p,      ra0);
                    unsafeAtomicAdd(p + 16, ra1);
                    unsafeAtomicAdd(p + 32, ra2);
                    unsafeAtomicAdd(p + 48, ra3);
                }
                ra0 = ra1 = ra2 = ra3 = 0.f; cur = rcv;
            }
            const float* sp = s_up + snd*64 + c;
            ra0 = fmaf(sp[0],  mixr[t][0] * msk, ra0);
            ra1 = fmaf(sp[16], mixr[t][1] * msk, ra1);
            ra2 = fmaf(sp[32], mixr[t][2] * msk, ra2);
            ra3 = fmaf(sp[48], mixr[t][3] * msk, ra3);
        }
        float* p = agg_s + cur*128 + c;
        unsafeAtomicAdd(p,      ra0);
        unsafeAtomicAdd(p + 16, ra1);
        unsafeAtomicAdd(p + 32, ra2);
        unsafeAtomicAdd(p + 48, ra3);
    } else if (wq == 1) {     // agg_s[:, 64+ntl*16+c] += (mv.Y)/sqrt3 * mix1
        float ra0=0.f, ra1=0.f, ra2=0.f, ra3=0.f;
        #pragma unroll
        for (int t = 0; t < 16; ++t) {
            const int sl  = (lane & 48) + t;
            const int rcv = __shfl(rcv_l, sl);
            const int snd = __shfl(snd_l, sl);
            const float msk = __shfl(msk_l, sl);
            const float Y0 = __shfl(Y0_l, sl), Y1 = __shfl(Y1_l, sl), Y2 = __shfl(Y2_l, sl);
            if (rcv != cur) {
                if (cur >= 0) {
                    float* p = agg_s + cur*128 + 64 + c;
                    unsafeAtomicAdd(p,      ra0);
                    unsafeAtomicAdd(p + 16, ra1);
                    unsafeAtomicAdd(p + 32, ra2);
                    unsafeAtomicAdd(p + 48, ra3);
                }
                ra0 = ra1 = ra2 = ra3 = 0.f; cur = rcv;
            }
            const float* vp = v_up + (snd*64 + c)*3;
            const float t00 = (vp[  0]*Y0 + vp[  1]*Y1 + vp[  2]*Y2) * INV_SQRT3_F;
            const float t01 = (vp[ 48]*Y0 + vp[ 49]*Y1 + vp[ 50]*Y2) * INV_SQRT3_F;
            const float t02 = (vp[ 96]*Y0 + vp[ 97]*Y1 + vp[ 98]*Y2) * INV_SQRT3_F;
            const float t03 = (vp[144]*Y0 + vp[145]*Y1 + vp[146]*Y2) * INV_SQRT3_F;
            ra0 = fmaf(t00, mixr[t][0] * msk, ra0);
            ra1 = fmaf(t01, mixr[t][1] * msk, ra1);
            ra2 = fmaf(t02, mixr[t][2] * msk, ra2);
            ra3 = fmaf(t03, mixr[t][3] * msk, ra3);
        }
        float* p = agg_s + cur*128 + 64 + c;
        unsafeAtomicAdd(p,      ra0);
        unsafeAtomicAdd(p + 16, ra1);
        unsafeAtomicAdd(p + 32, ra2);
        unsafeAtomicAdd(p + 48, ra3);
    } else if (wq == 2) {     // agg_v[:, ntl*16+c, m] += mv_m * mix2
        float rv[4][3];
        #pragma unroll
        for (int i = 0; i < 4; ++i) { rv[i][0]=0.f; rv[i][1]=0.f; rv[i][2]=0.f; }
        #pragma unroll
        for (int t = 0; t < 16; ++t) {
            const int sl  = (lane & 48) + t;
            const int rcv = __shfl(rcv_l, sl);
            const int snd = __shfl(snd_l, sl);
            const float msk = __shfl(msk_l, sl);
            if (rcv != cur) {
                if (cur >= 0) {
                    float* p = agg_v + cur*384 + c*3;
                    #pragma unroll
                    for (int ntl = 0; ntl < 4; ++ntl)
                        #pragma unroll
                        for (int m = 0; m < 3; ++m)
                            unsafeAtomicAdd(p + ntl*48 + m, rv[ntl][m]);
                }
                #pragma unroll
                for (int i = 0; i < 4; ++i) { rv[i][0]=0.f; rv[i][1]=0.f; rv[i][2]=0.f; }
                cur = rcv;
            }
            const float* vp = v_up + (snd*64 + c)*3;
            #pragma unroll
            for (int ntl = 0; ntl < 4; ++ntl) {
                const float mx = mixr[t][ntl] * msk;
                #pragma unroll
                for (int m = 0; m < 3; ++m)
                    rv[ntl][m] = fmaf(vp[ntl*48 + m], mx, rv[ntl][m]);
            }
        }
        float* p = agg_v + cur*384 + c*3;
        #pragma unroll
        for (int ntl = 0; ntl < 4; ++ntl)
            #pragma unroll
            for (int m = 0; m < 3; ++m)
                unsafeAtomicAdd(p + ntl*48 + m, rv[ntl][m]);
    } else {                  // agg_v[:, 64+ntl*16+c, m] += msv * Y_m * mix3
        float rv[4][3];
        #pragma unroll
        for (int i = 0; i < 4; ++i) { rv[i][0]=0.f; rv[i][1]=0.f; rv[i][2]=0.f; }
        #pragma unroll
        for (int t = 0; t < 16; ++t) {
            const int sl  = (lane & 48) + t;
            const int rcv = __shfl(rcv_l, sl);
            const int snd = __shfl(snd_l, sl);
            const float msk = __shfl(msk_l, sl);
            const float Y0 = __shfl(Y0_l, sl), Y1 = __shfl(Y1_l, sl), Y2 = __shfl(Y2_l, sl);
            if (rcv != cur) {
                if (cur >= 0) {
                    float* p = agg_v + cur*384 + 192 + c*3;
                    #pragma unroll
                    for (int ntl = 0; ntl < 4; ++ntl)
                        #pragma unroll
                        for (int m = 0; m < 3; ++m)
                            unsafeAtomicAdd(p + ntl*48 + m, rv[ntl][m]);
                }
                #pragma unroll
                for (int i = 0; i < 4; ++i) { rv[i][0]=0.f; rv[i][1]=0.f; rv[i][2]=0.f; }
                cur = rcv;
            }
            const float* sp = s_up + snd*64 + c;
            #pragma unroll
            for (int ntl = 0; ntl < 4; ++ntl) {
                const float mm = sp[ntl*16] * (mixr[t][ntl] * msk);
                rv[ntl][0] = fmaf(mm, Y0, rv[ntl][0]);
                rv[ntl][1] = fmaf(mm, Y1, rv[ntl][1]);
                rv[ntl][2] = fmaf(mm, Y2, rv[ntl][2]);
            }
        }
        float* p = agg_v + cur*384 + 192 + c*3;
        #pragma unroll
        for (int ntl = 0; ntl < 4; ++ntl)
            #pragma unroll
            for (int m = 0; m < 3; ++m)
                unsafeAtomicAdd(p + ntl*48 + m, rv[ntl][m]);
    }
}

// ---------------------------------------------------------------------------
// K3: node down-projection + specie skip + swish gating (round-2, known good).
// ---------------------------------------------------------------------------
__global__ __launch_bounds__(256) void k_node_down(
    const float* __restrict__ ns, const float* __restrict__ nv,
    const int*   __restrict__ spec_idx,
    const float* __restrict__ Wds, const float* __restrict__ Wdv,
    const float* __restrict__ Wsks, const float* __restrict__ Wskv,
    const float* __restrict__ agg_s, const float* __restrict__ agg_v,
    float* __restrict__ out)
{
    const int lane = threadIdx.x & 63;
    const int wq   = __builtin_amdgcn_readfirstlane(threadIdx.x >> 6);
    const int n    = blockIdx.x * 4 + wq;
    const int spec = __builtin_amdgcn_readfirstlane(spec_idx[n]);

    const float* ar  = agg_s + n*128;
    const float* avr = agg_v + n*384;
    float s0 = 0.f, s1 = 0.f, v0 = 0.f, v1 = 0.f, v2 = 0.f;
    for (int i = 0; i < 128; ++i) {
        const float a = ar[i] * INV_AVG;
        s0 = fmaf(a, Wds[i*128 + lane], s0);
        s1 = fmaf(a, Wds[i*128 + 64 + lane], s1);
        const float wv = Wdv[i*64 + lane];
        v0 = fmaf(avr[i*3+0] * INV_AVG, wv, v0);
        v1 = fmaf(avr[i*3+1] * INV_AVG, wv, v1);
        v2 = fmaf(avr[i*3+2] * INV_AVG, wv, v2);
    }
    const float* nsr = ns + n*64;
    const float* nvr = nv + n*192;
    const float* Ws  = Wsks + spec*8192;   // (64,128)
    const float* Wv  = Wskv + spec*4096;   // (64,64)
    for (int i = 0; i < 64; ++i) {
        const float s = nsr[i];
        s0 = fmaf(s, Ws[i*128 + lane], s0);
        s1 = fmaf(s, Ws[i*128 + 64 + lane], s1);
        const float wv = Wv[i*64 + lane];
        v0 = fmaf(nvr[i*3+0], wv, v0);
        v1 = fmaf(nvr[i*3+1], wv, v1);
        v2 = fmaf(nvr[i*3+2], wv, v2);
    }
    const float scal = swish_f(s0);
    const float gate = swish_f(s1);
    out[n*256 + lane]               = scal;
    out[n*256 + 64 + lane*3 + 0]    = v0 * gate;
    out[n*256 + 64 + lane*3 + 1]    = v1 * gate;
    out[n*256 + 64 + lane*3 + 2]    = v2 * gate;
}

// ---------------------------------------------------------------------------
extern "C" void kernel_launch(void* const* d_in, const int* in_sizes, int n_in,
                              void* d_out, int out_size, void* d_ws, size_t ws_size,
                              hipStream_t stream)
{
    (void)in_sizes; (void)n_in; (void)out_size; (void)ws_size;

    const float* vectors      = (const float*)d_in[0];
    const float* node_scalars = (const float*)d_in[1];
    const float* node_vectors = (const float*)d_in[2];
    const int*   node_specie  = (const int*)d_in[3];
    const int*   senders      = (const int*)d_in[4];
    const int*   receivers    = (const int*)d_in[5];
    const float* W_skip_s     = (const float*)d_in[6];
    const float* W_skip_v     = (const float*)d_in[7];
    const float* W_up_s       = (const float*)d_in[8];
    const float* W_up_v       = (const float*)d_in[9];
    const float* W_mlp0       = (const float*)d_in[10];
    const float* W_mlp1       = (const float*)d_in[11];
    const float* W_mlp2       = (const float*)d_in[12];
    const float* W_down_s     = (const float*)d_in[13];
    const float* W_down_v     = (const float*)d_in[14];
    float* out = (float*)d_out;

    // workspace layout (round-2): 15,360,000 f32 + perm 320k ints.
    float* ws    = (float*)d_ws;
    float* s_up  = ws;                        // N*64   = 1,280,000 f32
    float* v_up  = s_up + 1280000;            // N*192  = 3,840,000
    float* agg_s = v_up + 3840000;            // N*128  = 2,560,000
    float* agg_v = agg_s + 2560000;           // N*384  = 7,680,000
    int*   perm  = (int*)(agg_v + 7680000);   // E ints = 320,000
    int*   cnt    = (int*)agg_s;              // aliased scratch (dead before node_up)
    int*   cursor = cnt + 20000;

    // edge counting sort by receiver
    hipLaunchKernelGGL(k_zero_cnt, dim3(79),   dim3(256),  0, stream, cnt);
    hipLaunchKernelGGL(k_hist,     dim3(1250), dim3(256),  0, stream, receivers, cnt);
    hipLaunchKernelGGL(k_scan,     dim3(1),    dim3(1024), 0, stream, cnt, cursor);
    hipLaunchKernelGGL(k_scatter,  dim3(1250), dim3(256),  0, stream, receivers, cursor, perm);

    hipLaunchKernelGGL(k_node_up, dim3(5000), dim3(256), 0, stream,
        node_scalars, node_vectors, W_up_s, W_up_v, s_up, v_up, agg_s, agg_v);
    hipLaunchKernelGGL(k_edge, dim3(5000), dim3(256), 0, stream,
        vectors, senders, receivers, perm, W_mlp0, W_mlp1, W_mlp2,
        s_up, v_up, agg_s, agg_v);
    hipLaunchKernelGGL(k_node_down, dim3(5000), dim3(256), 0, stream,
        node_scalars, node_vectors, node_specie, W_down_s, W_down_v,
        W_skip_s, W_skip_v, agg_s, agg_v, out);
}

// Round 2
// 529.086 us; speedup vs baseline: 3.9750x; 3.9750x over previous
//
#include <hip/hip_runtime.h>
#include <math.h>

// Problem constants: N=20000, E=320000, C=64, NS=4, NB=8, NH=64
#define PI_F        3.14159265358979323846f
#define SQRT2_F     1.41421356237309515f
#define SQRT3_F     1.73205080756887729f
#define INV_SQRT3_F 0.57735026918962576f
#define INV_AVG     0.25f   // 1/sqrt(16)

#define N_NODES 20000
#define N_EDGES 320000

typedef float v2f __attribute__((ext_vector_type(2)));
typedef float v4f __attribute__((ext_vector_type(4)));

__device__ __forceinline__ float swish_f(float x) {
    return x / (1.f + __expf(-x));
}

// ---------------------------------------------------------------------------
// Edge counting sort by receiver (round-2, known good).
// ---------------------------------------------------------------------------
__global__ __launch_bounds__(256) void k_zero_cnt(int* __restrict__ cnt) {
    const int i = blockIdx.x * 256 + threadIdx.x;
    if (i < N_NODES) cnt[i] = 0;
}
__global__ __launch_bounds__(256) void k_hist(const int* __restrict__ rcv,
                                              int* __restrict__ cnt) {
    const int e = blockIdx.x * 256 + threadIdx.x;
    if (e < N_EDGES) atomicAdd(&cnt[rcv[e]], 1);
}
__global__ __launch_bounds__(1024) void k_scan(const int* __restrict__ cnt,
                                               int* __restrict__ cursor) {
    __shared__ int part[1024];
    const int t = threadIdx.x;
    const int base = t * 20;
    int s = 0;
    #pragma unroll
    for (int j = 0; j < 20; ++j) {
        const int idx = base + j;
        if (idx < N_NODES) s += cnt[idx];
    }
    part[t] = s;
    __syncthreads();
    for (int d = 1; d < 1024; d <<= 1) {
        const int v = (t >= d) ? part[t - d] : 0;
        __syncthreads();
        part[t] += v;
        __syncthreads();
    }
    int run = (t == 0) ? 0 : part[t - 1];
    for (int j = 0; j < 20; ++j) {
        const int idx = base + j;
        if (idx < N_NODES) { cursor[idx] = run; run += cnt[idx]; }
    }
}
__global__ __launch_bounds__(256) void k_scatter(const int* __restrict__ rcv,
                                                 int* __restrict__ cursor,
                                                 int* __restrict__ perm) {
    const int e = blockIdx.x * 256 + threadIdx.x;
    if (e < N_EDGES) {
        const int pos = atomicAdd(&cursor[rcv[e]], 1);
        perm[pos] = e;
    }
}

// ---------------------------------------------------------------------------
// K1: node up-projection + agg zero-init (round-2, known good).
// ---------------------------------------------------------------------------
__global__ __launch_bounds__(256) void k_node_up(
    const float* __restrict__ ns, const float* __restrict__ nv,
    const float* __restrict__ Wus, const float* __restrict__ Wuv,
    float* __restrict__ s_up, float* __restrict__ v_up,
    float* __restrict__ agg_s, float* __restrict__ agg_v)
{
    const int lane = threadIdx.x & 63;
    const int wq   = __builtin_amdgcn_readfirstlane(threadIdx.x >> 6);
    const int n    = blockIdx.x * 4 + wq;

    const float* nsr = ns + n * 64;
    const float* nvr = nv + n * 192;
    float acc = 0.f, a0 = 0.f, a1 = 0.f, a2 = 0.f;
    for (int i = 0; i < 64; ++i) {
        const float s = nsr[i];
        acc = fmaf(s, Wus[i*64 + lane], acc);
        const float wv = Wuv[i*64 + lane];
        a0 = fmaf(nvr[i*3+0], wv, a0);
        a1 = fmaf(nvr[i*3+1], wv, a1);
        a2 = fmaf(nvr[i*3+2], wv, a2);
    }
    s_up[n*64 + lane] = acc;
    v_up[(n*64 + lane)*3 + 0] = a0;
    v_up[(n*64 + lane)*3 + 1] = a1;
    v_up[(n*64 + lane)*3 + 2] = a2;

    agg_s[n*128 + lane]      = 0.f;
    agg_s[n*128 + 64 + lane] = 0.f;
    #pragma unroll
    for (int k = 0; k < 6; ++k) agg_v[n*384 + k*64 + lane] = 0.f;
}

// ---------------------------------------------------------------------------
// K2 v8 (VALU-CUT): back to the known-good (256,4) register regime of v6
// (the (256,8) attempt in v7 forced <=64 total regs -> mixr[16][4] spilled
// to scratch: WRITE_SIZE 197MB->5.9GB, VALUBusy 74%->11%, 288->1845us).
// Changes vs v6, keeping scaffold + phase-C identical:
//  * LDS h buffer TRANSPOSED to [channel][edge], stride 68 (16B-aligned
//    rows): the 16 h values each lane consumes per i-step are contiguous ->
//    ds_read_b128. A2+B ds ops drop 4x (2048 -> 512 b128/wave). B-reads
//    2-way bank-aliased (free); A1/A2 column writes 8-way but only 8
//    instrs/lane.
//  * Packed f32 FMA: accumulators paired over adjacent t (adjacent in the
//    b128 payload) via float2 + __builtin_elementwise_fma -> v_pk_fma_f32.
//    Phase B 4096 fma -> 2048 pk_fma; A2 1024 -> 512.
//  * Single in-place h buffer kept (A2 of wave wq reads cols wq*16..+15 of
//    all rows fully before overwriting those same cols; cols disjoint per
//    wave; phase B covered by __syncthreads). 17,408 B LDS.
//  * Precise swish restored (v7's rcpf doubled absmax).
// ---------------------------------------------------------------------------
__global__ __launch_bounds__(256, 4) void k_edge(
    const float* __restrict__ vecs,
    const int*   __restrict__ snd_idx, const int* __restrict__ rcv_idx,
    const int*   __restrict__ perm,
    const float* __restrict__ W0, const float* __restrict__ W1,
    const float* __restrict__ W2,
    const float* __restrict__ s_up, const float* __restrict__ v_up,
    float* __restrict__ agg_s, float* __restrict__ agg_v)
{
    __shared__ float hv[64*68];   // [ch][le], stride 68; holds h1 then h2

    const int tid  = threadIdx.x;
    const int lane = tid & 63;
    const int wq   = __builtin_amdgcn_readfirstlane(tid >> 6);
    const int e0   = blockIdx.x * 64;
    const int c    = lane & 15, q = lane >> 4;

    // --- per-lane metadata for sorted slot e0+lane (all 64 edges) ---
    const int pe_l  = perm[e0 + lane];
    const int rcv_l = rcv_idx[pe_l];
    const int snd_l = snd_idx[pe_l];
    const float vx_l = vecs[pe_l*3+0], vy_l = vecs[pe_l*3+1], vz_l = vecs[pe_l*3+2];
    const float x_l  = sqrtf(vx_l*vx_l + vy_l*vy_l + vz_l*vz_l);
    const float sx_l = (x_l == 0.f) ? 1.f : x_l;
    const float ys_l = SQRT3_F / sx_l;
    const float Y0_l = vx_l * ys_l, Y1_l = vy_l * ys_l, Y2_l = vz_l * ys_l;
    const float msk_l = (x_l == 0.f) ? 0.f : 1.f;

    // ---- A1: bessel + layer0 -> h1, channel=lane, edges le=wq*16+t ----
    float h1o[16];
    #pragma unroll 4
    for (int t = 0; t < 16; ++t) {
        const int le = wq*16 + t;
        const float x = __shfl(x_l, le);
        const float sx = (x == 0.f) ? 1.f : x;
        float s1, c1;
        __sincosf(PI_F * x, &s1, &c1);
        const float u  = fminf(x, 1.f);
        const float u2 = u*u, u3 = u2*u;
        const float u6 = u3*u3, u7 = u6*u, u8 = u6*u2;
        const float env  = (x < 1.f) ? (1.f - 28.f*u6 + 48.f*u7 - 21.f*u8) : 0.f;
        const float pref = SQRT2_F * env / sx;
        float h1 = 0.f;
        float sn = s1, snm1 = 0.f;
        const float twoc = 2.f * c1;
        #pragma unroll
        for (int b = 0; b < 8; ++b) {
            h1 = fmaf(pref * sn, W0[b*64 + lane], h1);
            const float snext = fmaf(twoc, sn, -snm1);
            snm1 = sn; sn = snext;
        }
        h1o[t] = swish_f(h1);
    }
    {   // write own channel-row, own wave's 16 edge-columns: 4x ds_write_b128
        float* dst = hv + lane*68 + wq*16;
        #pragma unroll
        for (int k = 0; k < 4; ++k)
            ((v4f*)dst)[k] = (v4f){h1o[4*k], h1o[4*k+1], h1o[4*k+2], h1o[4*k+3]};
    }
    // no barrier: A2 reads only columns wq*16..+15, written by this wave.

    // ---- A2: h2 = swish(h1 @ W1); reads all rows i fully, then overwrites
    //      own row (=lane) of the same columns. lane = output channel.
    {
        v2f acc2[8];
        #pragma unroll
        for (int tp = 0; tp < 8; ++tp) acc2[tp] = (v2f){0.f, 0.f};
        const float* hbase = hv + wq*16;
        for (int i = 0; i < 64; ++i) {
            const float w = W1[i*64 + lane];           // coalesced, L1-hot
            const v2f wv = {w, w};
            const v4f* hp4 = (const v4f*)(hbase + i*68);
            #pragma unroll
            for (int k = 0; k < 4; ++k) {
                const v4f h4 = hp4[k];
                const v2f hlo = __builtin_shufflevector(h4, h4, 0, 1);
                const v2f hhi = __builtin_shufflevector(h4, h4, 2, 3);
                acc2[2*k]   = __builtin_elementwise_fma(hlo, wv, acc2[2*k]);
                acc2[2*k+1] = __builtin_elementwise_fma(hhi, wv, acc2[2*k+1]);
            }
        }
        float* dst = hv + lane*68 + wq*16;
        #pragma unroll
        for (int k = 0; k < 4; ++k)
            ((v4f*)dst)[k] = (v4f){swish_f(acc2[2*k][0]),   swish_f(acc2[2*k][1]),
                                   swish_f(acc2[2*k+1][0]), swish_f(acc2[2*k+1][1])};
    }
    __syncthreads();

    // ---- B: mixp[t/2][ntl] pairs; lane (c,q) of wave wq accumulates
    //      mix[64wq + ntl*16 + c][le = q*16 + t] for t=0..15.
    v2f mixp[8][4];
    #pragma unroll
    for (int tp = 0; tp < 8; ++tp)
        #pragma unroll
        for (int j = 0; j < 4; ++j) mixp[tp][j] = (v2f){0.f, 0.f};
    {
        const float* W2c = W2 + 64*wq + c;
        const float* hq  = hv + q*16;
        for (int i = 0; i < 64; ++i) {
            const float w0 = W2c[i*256 +  0];
            const float w1 = W2c[i*256 + 16];
            const float w2 = W2c[i*256 + 32];
            const float w3 = W2c[i*256 + 48];
            const v2f w0v = {w0,w0}, w1v = {w1,w1}, w2v = {w2,w2}, w3v = {w3,w3};
            const v4f* hp4 = (const v4f*)(hq + i*68);
            #pragma unroll
            for (int k = 0; k < 4; ++k) {
                const v4f h4 = hp4[k];
                const v2f hlo = __builtin_shufflevector(h4, h4, 0, 1);
                const v2f hhi = __builtin_shufflevector(h4, h4, 2, 3);
                mixp[2*k][0]   = __builtin_elementwise_fma(hlo, w0v, mixp[2*k][0]);
                mixp[2*k][1]   = __builtin_elementwise_fma(hlo, w1v, mixp[2*k][1]);
                mixp[2*k][2]   = __builtin_elementwise_fma(hlo, w2v, mixp[2*k][2]);
                mixp[2*k][3]   = __builtin_elementwise_fma(hlo, w3v, mixp[2*k][3]);
                mixp[2*k+1][0] = __builtin_elementwise_fma(hhi, w0v, mixp[2*k+1][0]);
                mixp[2*k+1][1] = __builtin_elementwise_fma(hhi, w1v, mixp[2*k+1][1]);
                mixp[2*k+1][2] = __builtin_elementwise_fma(hhi, w2v, mixp[2*k+1][2]);
                mixp[2*k+1][3] = __builtin_elementwise_fma(hhi, w3v, mixp[2*k+1][3]);
            }
        }
    }
    #define MIXR(t,j) (mixp[(t)>>1][j][(t)&1])

    // ---- C: per-q-group segmented scatter-add from registers (v5) ----
    int cur = -1;
    if (wq == 0) {            // agg_s[:, ntl*16+c] += msv * mix0
        float ra0=0.f, ra1=0.f, ra2=0.f, ra3=0.f;
        #pragma unroll
        for (int t = 0; t < 16; ++t) {
            const int sl  = (lane & 48) + t;
            const int rcv = __shfl(rcv_l, sl);
            const int snd = __shfl(snd_l, sl);
            const float msk = __shfl(msk_l, sl);
            if (rcv != cur) {
                if (cur >= 0) {
                    float* p = agg_s + cur*128 + c;
                    unsafeAtomicAdd(p,      ra0);
                    unsafeAtomicAdd(p + 16, ra1);
                    unsafeAtomicAdd(p + 32, ra2);
                    unsafeAtomicAdd(p + 48, ra3);
                }
                ra0 = ra1 = ra2 = ra3 = 0.f; cur = rcv;
            }
            const float* sp = s_up + snd*64 + c;
            ra0 = fmaf(sp[0],  MIXR(t,0) * msk, ra0);
            ra1 = fmaf(sp[16], MIXR(t,1) * msk, ra1);
            ra2 = fmaf(sp[32], MIXR(t,2) * msk, ra2);
            ra3 = fmaf(sp[48], MIXR(t,3) * msk, ra3);
        }
        float* p = agg_s + cur*128 + c;
        unsafeAtomicAdd(p,      ra0);
        unsafeAtomicAdd(p + 16, ra1);
        unsafeAtomicAdd(p + 32, ra2);
        unsafeAtomicAdd(p + 48, ra3);
    } else if (wq == 1) {     // agg_s[:, 64+ntl*16+c] += (mv.Y)/sqrt3 * mix1
        float ra0=0.f, ra1=0.f, ra2=0.f, ra3=0.f;
        #pragma unroll
        for (int t = 0; t < 16; ++t) {
            const int sl  = (lane & 48) + t;
            const int rcv = __shfl(rcv_l, sl);
            const int snd = __shfl(snd_l, sl);
            const float msk = __shfl(msk_l, sl);
            const float Y0 = __shfl(Y0_l, sl), Y1 = __shfl(Y1_l, sl), Y2 = __shfl(Y2_l, sl);
            if (rcv != cur) {
                if (cur >= 0) {
                    float* p = agg_s + cur*128 + 64 + c;
                    unsafeAtomicAdd(p,      ra0);
                    unsafeAtomicAdd(p + 16, ra1);
                    unsafeAtomicAdd(p + 32, ra2);
                    unsafeAtomicAdd(p + 48, ra3);
                }
                ra0 = ra1 = ra2 = ra3 = 0.f; cur = rcv;
            }
            const float* vp = v_up + (snd*64 + c)*3;
            const float t00 = (vp[  0]*Y0 + vp[  1]*Y1 + vp[  2]*Y2) * INV_SQRT3_F;
            const float t01 = (vp[ 48]*Y0 + vp[ 49]*Y1 + vp[ 50]*Y2) * INV_SQRT3_F;
            const float t02 = (vp[ 96]*Y0 + vp[ 97]*Y1 + vp[ 98]*Y2) * INV_SQRT3_F;
            const float t03 = (vp[144]*Y0 + vp[145]*Y1 + vp[146]*Y2) * INV_SQRT3_F;
            ra0 = fmaf(t00, MIXR(t,0) * msk, ra0);
            ra1 = fmaf(t01, MIXR(t,1) * msk, ra1);
            ra2 = fmaf(t02, MIXR(t,2) * msk, ra2);
            ra3 = fmaf(t03, MIXR(t,3) * msk, ra3);
        }
        float* p = agg_s + cur*128 + 64 + c;
        unsafeAtomicAdd(p,      ra0);
        unsafeAtomicAdd(p + 16, ra1);
        unsafeAtomicAdd(p + 32, ra2);
        unsafeAtomicAdd(p + 48, ra3);
    } else if (wq == 2) {     // agg_v[:, ntl*16+c, m] += mv_m * mix2
        float rv[4][3];
        #pragma unroll
        for (int i = 0; i < 4; ++i) { rv[i][0]=0.f; rv[i][1]=0.f; rv[i][2]=0.f; }
        #pragma unroll
        for (int t = 0; t < 16; ++t) {
            const int sl  = (lane & 48) + t;
            const int rcv = __shfl(rcv_l, sl);
            const int snd = __shfl(snd_l, sl);
            const float msk = __shfl(msk_l, sl);
            if (rcv != cur) {
                if (cur >= 0) {
                    float* p = agg_v + cur*384 + c*3;
                    #pragma unroll
                    for (int ntl = 0; ntl < 4; ++ntl)
                        #pragma unroll
                        for (int m = 0; m < 3; ++m)
                            unsafeAtomicAdd(p + ntl*48 + m, rv[ntl][m]);
                }
                #pragma unroll
                for (int i = 0; i < 4; ++i) { rv[i][0]=0.f; rv[i][1]=0.f; rv[i][2]=0.f; }
                cur = rcv;
            }
            const float* vp = v_up + (snd*64 + c)*3;
            #pragma unroll
            for (int ntl = 0; ntl < 4; ++ntl) {
                const float mx = MIXR(t,ntl) * msk;
                #pragma unroll
                for (int m = 0; m < 3; ++m)
                    rv[ntl][m] = fmaf(vp[ntl*48 + m], mx, rv[ntl][m]);
            }
        }
        float* p = agg_v + cur*384 + c*3;
        #pragma unroll
        for (int ntl = 0; ntl < 4; ++ntl)
            #pragma unroll
            for (int m = 0; m < 3; ++m)
                unsafeAtomicAdd(p + ntl*48 + m, rv[ntl][m]);
    } else {                  // agg_v[:, 64+ntl*16+c, m] += msv * Y_m * mix3
        float rv[4][3];
        #pragma unroll
        for (int i = 0; i < 4; ++i) { rv[i][0]=0.f; rv[i][1]=0.f; rv[i][2]=0.f; }
        #pragma unroll
        for (int t = 0; t < 16; ++t) {
            const int sl  = (lane & 48) + t;
            const int rcv = __shfl(rcv_l, sl);
            const int snd = __shfl(snd_l, sl);
            const float msk = __shfl(msk_l, sl);
            const float Y0 = __shfl(Y0_l, sl), Y1 = __shfl(Y1_l, sl), Y2 = __shfl(Y2_l, sl);
            if (rcv != cur) {
                if (cur >= 0) {
                    float* p = agg_v + cur*384 + 192 + c*3;
                    #pragma unroll
                    for (int ntl = 0; ntl < 4; ++ntl)
                        #pragma unroll
                        for (int m = 0; m < 3; ++m)
                            unsafeAtomicAdd(p + ntl*48 + m, rv[ntl][m]);
                }
                #pragma unroll
                for (int i = 0; i < 4; ++i) { rv[i][0]=0.f; rv[i][1]=0.f; rv[i][2]=0.f; }
                cur = rcv;
            }
            const float* sp = s_up + snd*64 + c;
            #pragma unroll
            for (int ntl = 0; ntl < 4; ++ntl) {
                const float mm = sp[ntl*16] * (MIXR(t,ntl) * msk);
                rv[ntl][0] = fmaf(mm, Y0, rv[ntl][0]);
                rv[ntl][1] = fmaf(mm, Y1, rv[ntl][1]);
                rv[ntl][2] = fmaf(mm, Y2, rv[ntl][2]);
            }
        }
        float* p = agg_v + cur*384 + 192 + c*3;
        #pragma unroll
        for (int ntl = 0; ntl < 4; ++ntl)
            #pragma unroll
            for (int m = 0; m < 3; ++m)
                unsafeAtomicAdd(p + ntl*48 + m, rv[ntl][m]);
    }
    #undef MIXR
}

// ---------------------------------------------------------------------------
// K3: node down-projection + specie skip + swish gating (round-2, known good).
// ---------------------------------------------------------------------------
__global__ __launch_bounds__(256) void k_node_down(
    const float* __restrict__ ns, const float* __restrict__ nv,
    const int*   __restrict__ spec_idx,
    const float* __restrict__ Wds, const float* __restrict__ Wdv,
    const float* __restrict__ Wsks, const float* __restrict__ Wskv,
    const float* __restrict__ agg_s, const float* __restrict__ agg_v,
    float* __restrict__ out)
{
    const int lane = threadIdx.x & 63;
    const int wq   = __builtin_amdgcn_readfirstlane(threadIdx.x >> 6);
    const int n    = blockIdx.x * 4 + wq;
    const int spec = __builtin_amdgcn_readfirstlane(spec_idx[n]);

    const float* ar  = agg_s + n*128;
    const float* avr = agg_v + n*384;
    float s0 = 0.f, s1 = 0.f, v0 = 0.f, v1 = 0.f, v2 = 0.f;
    for (int i = 0; i < 128; ++i) {
        const float a = ar[i] * INV_AVG;
        s0 = fmaf(a, Wds[i*128 + lane], s0);
        s1 = fmaf(a, Wds[i*128 + 64 + lane], s1);
        const float wv = Wdv[i*64 + lane];
        v0 = fmaf(avr[i*3+0] * INV_AVG, wv, v0);
        v1 = fmaf(avr[i*3+1] * INV_AVG, wv, v1);
        v2 = fmaf(avr[i*3+2] * INV_AVG, wv, v2);
    }
    const float* nsr = ns + n*64;
    const float* nvr = nv + n*192;
    const float* Ws  = Wsks + spec*8192;   // (64,128)
    const float* Wv  = Wskv + spec*4096;   // (64,64)
    for (int i = 0; i < 64; ++i) {
        const float s = nsr[i];
        s0 = fmaf(s, Ws[i*128 + lane], s0);
        s1 = fmaf(s, Ws[i*128 + 64 + lane], s1);
        const float wv = Wv[i*64 + lane];
        v0 = fmaf(nvr[i*3+0], wv, v0);
        v1 = fmaf(nvr[i*3+1], wv, v1);
        v2 = fmaf(nvr[i*3+2], wv, v2);
    }
    const float scal = swish_f(s0);
    const float gate = swish_f(s1);
    out[n*256 + lane]               = scal;
    out[n*256 + 64 + lane*3 + 0]    = v0 * gate;
    out[n*256 + 64 + lane*3 + 1]    = v1 * gate;
    out[n*256 + 64 + lane*3 + 2]    = v2 * gate;
}

// ---------------------------------------------------------------------------
extern "C" void kernel_launch(void* const* d_in, const int* in_sizes, int n_in,
                              void* d_out, int out_size, void* d_ws, size_t ws_size,
                              hipStream_t stream)
{
    (void)in_sizes; (void)n_in; (void)out_size; (void)ws_size;

    const float* vectors      = (const float*)d_in[0];
    const float* node_scalars = (const float*)d_in[1];
    const float* node_vectors = (const float*)d_in[2];
    const int*   node_specie  = (const int*)d_in[3];
    const int*   senders      = (const int*)d_in[4];
    const int*   receivers    = (const int*)d_in[5];
    const float* W_skip_s     = (const float*)d_in[6];
    const float* W_skip_v     = (const float*)d_in[7];
    const float* W_up_s       = (const float*)d_in[8];
    const float* W_up_v       = (const float*)d_in[9];
    const float* W_mlp0       = (const float*)d_in[10];
    const float* W_mlp1       = (const float*)d_in[11];
    const float* W_mlp2       = (const float*)d_in[12];
    const float* W_down_s     = (const float*)d_in[13];
    const float* W_down_v     = (const float*)d_in[14];
    float* out = (float*)d_out;

    // workspace layout (round-2): 15,360,000 f32 + perm 320k ints.
    float* ws    = (float*)d_ws;
    float* s_up  = ws;                        // N*64   = 1,280,000 f32
    float* v_up  = s_up + 1280000;            // N*192  = 3,840,000
    float* agg_s = v_up + 3840000;            // N*128  = 2,560,000
    float* agg_v = agg_s + 2560000;           // N*384  = 7,680,000
    int*   perm  = (int*)(agg_v + 7680000);   // E ints = 320,000
    int*   cnt    = (int*)agg_s;              // aliased scratch (dead before node_up)
    int*   cursor = cnt + 20000;

    // edge counting sort by receiver
    hipLaunchKernelGGL(k_zero_cnt, dim3(79),   dim3(256),  0, stream, cnt);
    hipLaunchKernelGGL(k_hist,     dim3(1250), dim3(256),  0, stream, receivers, cnt);
    hipLaunchKernelGGL(k_scan,     dim3(1),    dim3(1024), 0, stream, cnt, cursor);
    hipLaunchKernelGGL(k_scatter,  dim3(1250), dim3(256),  0, stream, receivers, cursor, perm);

    hipLaunchKernelGGL(k_node_up, dim3(5000), dim3(256), 0, stream,
        node_scalars, node_vectors, W_up_s, W_up_v, s_up, v_up, agg_s, agg_v);
    hipLaunchKernelGGL(k_edge, dim3(5000), dim3(256), 0, stream,
        vectors, senders, receivers, perm, W_mlp0, W_mlp1, W_mlp2,
        s_up, v_up, agg_s, agg_v);
    hipLaunchKernelGGL(k_node_down, dim3(5000), dim3(256), 0, stream,
        node_scalars, node_vectors, node_specie, W_down_s, W_down_v,
        W_skip_s, W_skip_v, agg_s, agg_v, out);
}